// Round 6
// baseline (347.003 us; speedup 1.0000x reference)
//
#include <hip/hip_runtime.h>

// MultiHeadAttention: B=4, S=2048, E=1024, H=16, DK=64. fp32 in/out, bf16 MFMA internally.
//
// Pipeline (5 dispatches):
//   cvt_x:    x fp32 -> bf16
//   cvt_w:    Wq,Wk,Wv,Wo fp32 -> bf16 (Wq scaled by 1/sqrt(64)*log2(e) => softmax in exp2 domain)
//   gemm_qkv: Q,K = x@W^T -> (b*H+h, s, d); V = x@Wv^T -> (b*H+h, d, s) transposed  [one dispatch]
//   attn:     flash attention, 128 q-rows/block (32/wave), 64-key KV tiles, NO-MAX softmax
//             (scores bounded ~|9| in exp2 domain), native v_exp_f32, truncated-bf16 P.
//   gemm_bt<3>: out = ctx@Wo^T -> fp32
//
// R6: GEMM K-loop restructured to ping-pong LDS dbuf with ONE barrier per iter (stage k+1
// issued BEFORE compute on k -> the s_waitcnt vmcnt(0) drain at the barrier overlaps the
// compute phase; R5 counters showed ~900 cyc/iter of exposed drain: MfmaUtil 16.8 /
// VALU 21 / HBM 10 all idle). attn: P un-aliased into its own region, deleting the
// post-score barrier (existed only to fence the Ksm alias).
//
// MFMA 16x16x32 bf16 layouts (learn_hip verified):
//   A: lane holds A[m=lane&15][k=(lane>>4)*8+j]   B: lane holds B[k=(lane>>4)*8+j][n=lane&15]
//   C/D: col=lane&15, row=(lane>>4)*4+reg
// LDS tiles chunk-major [k-chunk][row][8 elems] -> b128 reads phase-complete (conflict floor).

typedef __bf16 bf16x8 __attribute__((ext_vector_type(8)));
typedef __bf16 bf16x4 __attribute__((ext_vector_type(4)));
typedef float floatx4 __attribute__((ext_vector_type(4)));

#define GLOAD_LDS16(gp, lp) __builtin_amdgcn_global_load_lds( \
    (const __attribute__((address_space(1))) unsigned int*)(gp), \
    (__attribute__((address_space(3))) unsigned int*)(lp), 16, 0, 0)

// ---------------------------------------------------------------- convert ----
__global__ __launch_bounds__(256) void cvt_x(const float4* __restrict__ s,
                                             bf16x4* __restrict__ d, int n4) {
    int i = blockIdx.x * 256 + threadIdx.x;
    if (i < n4) {
        float4 v = s[i];
        bf16x4 o = { (__bf16)v.x, (__bf16)v.y, (__bf16)v.z, (__bf16)v.w };
        d[i] = o;
    }
}

__global__ __launch_bounds__(256) void cvt_w(const float4* __restrict__ Wq,
                                             const float4* __restrict__ Wk,
                                             const float4* __restrict__ Wv,
                                             const float4* __restrict__ Wo,
                                             bf16x4* __restrict__ oq, bf16x4* __restrict__ ok,
                                             bf16x4* __restrict__ ov, bf16x4* __restrict__ oo,
                                             float qscale) {
    int y = blockIdx.y;
    const float4* s = (y == 0) ? Wq : (y == 1) ? Wk : (y == 2) ? Wv : Wo;
    bf16x4* d = (y == 0) ? oq : (y == 1) ? ok : (y == 2) ? ov : oo;
    float scale = (y == 0) ? qscale : 1.0f;
    int i = blockIdx.x * 256 + threadIdx.x;  // 262144 float4 per matrix
    float4 v = s[i];
    bf16x4 o = { (__bf16)(v.x * scale), (__bf16)(v.y * scale),
                 (__bf16)(v.z * scale), (__bf16)(v.w * scale) };
    d[i] = o;
}

// ---------------------------------------------------------------- GEMM core --
// C[m][n] = sum_k A[m][k] * W[n][k], M=8192, N=1024, K=1024. 128x128 tile, BK=32.
// SM layout (bf16 elems): buf0 A @0, B @4096; buf1 A @8192, B @12288. 32 KB total.
// Single barrier per K-iter: stage(k+1 -> buf^1); compute(buf); __syncthreads().
//   - compute(buf) safe: staging of buf was issued in iter k-1, drained by its barrier.
//   - stage(buf^1) safe: reads of buf^1 finished in iter k-1 before its barrier.

__device__ __forceinline__ void gemm_stage(const __bf16* __restrict__ A,
                                           const __bf16* __restrict__ W,
                                           __bf16* SM, int buf,
                                           int bm, int bn, int k0,
                                           int w, int lane) {
#pragma unroll
    for (int j = 0; j < 2; ++j) {
        int base = j * 256 + w * 64;      // wave-uniform cell index
        int flat = base + lane;
        int c = flat >> 7, r = flat & 127;
        GLOAD_LDS16(A + (size_t)(bm + r) * 1024 + k0 + c * 8,
                    (char*)(SM + buf * 8192) + base * 16);
        GLOAD_LDS16(W + (size_t)(bn + r) * 1024 + k0 + c * 8,
                    (char*)(SM + buf * 8192 + 4096) + base * 16);
    }
}

__device__ __forceinline__ void gemm_mainloop(const __bf16* __restrict__ A,
                                              const __bf16* __restrict__ W,
                                              __bf16* SM,
                                              int bm, int bn, int tid,
                                              floatx4 acc[4][4]) {
    const int w = tid >> 6, lane = tid & 63;
    const int quad = lane >> 4, l15 = lane & 15;
    const int wy = w >> 1, wx = w & 1;
#pragma unroll
    for (int i = 0; i < 4; ++i)
#pragma unroll
        for (int j = 0; j < 4; ++j) acc[i][j] = (floatx4){0.f, 0.f, 0.f, 0.f};

    gemm_stage(A, W, SM, 0, bm, bn, 0, w, lane);
    __syncthreads();  // prologue staging complete

    for (int k = 0; k < 32; ++k) {
        if (k + 1 < 32) gemm_stage(A, W, SM, (k + 1) & 1, bm, bn, (k + 1) * 32, w, lane);

        const __bf16* Asm = SM + (k & 1) * 8192;
        const __bf16* Bsm = Asm + 4096;
        bf16x8 af[4], bf[4];
#pragma unroll
        for (int mt = 0; mt < 4; ++mt)
            af[mt] = *(const bf16x8*)(Asm + (quad * 128 + wy * 64 + mt * 16 + l15) * 8);
#pragma unroll
        for (int nt = 0; nt < 4; ++nt)
            bf[nt] = *(const bf16x8*)(Bsm + (quad * 128 + wx * 64 + nt * 16 + l15) * 8);
#pragma unroll
        for (int mt = 0; mt < 4; ++mt)
#pragma unroll
            for (int nt = 0; nt < 4; ++nt)
                acc[mt][nt] = __builtin_amdgcn_mfma_f32_16x16x32_bf16(af[mt], bf[nt],
                                                                      acc[mt][nt], 0, 0, 0);
        __syncthreads();  // drains next-tile staging (overlapped w/ compute above);
                          // joins waves so buf^1 is safe to restage next iter
    }
    // loop exits post-barrier: no pending LDS reads; SM reusable as epilogue scratch
}

// Fused QKV: grid (64, 24). blockIdx.y: 0..7 -> Q, 8..15 -> K, 16..23 -> V(transposed out).
__global__ __launch_bounds__(256, 5) void gemm_qkv(const __bf16* __restrict__ A,
                                                   const __bf16* __restrict__ Wqb,
                                                   const __bf16* __restrict__ Wkb,
                                                   const __bf16* __restrict__ Wvb,
                                                   __bf16* __restrict__ Qg,
                                                   __bf16* __restrict__ Kg,
                                                   __bf16* __restrict__ Vtg) {
    __shared__ alignas(16) __bf16 SM[16384];   // 32 KB: 2 x (A 8KB + B 8KB)
    const int sel = blockIdx.y >> 3;                      // block-uniform
    const __bf16* W = (sel == 0) ? Wqb : (sel == 1) ? Wkb : Wvb;
    __bf16* ob = (sel == 0) ? Qg : (sel == 1) ? Kg : Vtg;
    const int bm = blockIdx.x * 128, bn = (blockIdx.y & 7) * 128;
    const int tid = threadIdx.x;
    const int w = tid >> 6, lane = tid & 63;
    const int quad = lane >> 4, l15 = lane & 15;
    const int wy = w >> 1, wx = w & 1;

    floatx4 acc[4][4];
    gemm_mainloop(A, W, SM, bm, bn, tid, acc);

    // bf16 epilogue via per-wave LDS transpose -> 8B stores
    float* tb = (float*)SM + w * 272;  // [16][17] per wave
    const int rr = lane >> 2, c0 = (lane & 3) * 4;
#pragma unroll
    for (int mt = 0; mt < 4; ++mt)
#pragma unroll
        for (int nt = 0; nt < 4; ++nt) {
            if (sel == 2) {
#pragma unroll
                for (int r = 0; r < 4; ++r) tb[l15 * 17 + quad * 4 + r] = acc[mt][nt][r];
            } else {
#pragma unroll
                for (int r = 0; r < 4; ++r) tb[(quad * 4 + r) * 17 + l15] = acc[mt][nt][r];
            }
            // wave-lockstep: DS pipe in-order within a wave
            float f0 = tb[rr * 17 + c0 + 0], f1 = tb[rr * 17 + c0 + 1];
            float f2 = tb[rr * 17 + c0 + 2], f3 = tb[rr * 17 + c0 + 3];
            bf16x4 pk = { (__bf16)f0, (__bf16)f1, (__bf16)f2, (__bf16)f3 };
            if (sel <= 1) {
                int m = bm + wy * 64 + mt * 16 + rr;      // s-row
                int n0 = bn + wx * 64 + nt * 16 + c0;     // 4 consecutive d
                int bI = m >> 11, s = m & 2047, h = n0 >> 6, d0 = n0 & 63;
                *(bf16x4*)(ob + ((size_t)(bI * 16 + h) * 2048 + s) * 64 + d0) = pk;
            } else {
                int m0 = bm + wy * 64 + mt * 16 + c0;     // 4 consecutive s
                int n = bn + wx * 64 + nt * 16 + rr;      // d-row
                int bI = m0 >> 11, s0 = m0 & 2047, h = n >> 6, d = n & 63;
                *(bf16x4*)(ob + ((size_t)(bI * 16 + h) * 64 + d) * 2048 + s0) = pk;
            }
        }
}

// MODE 3: fp32 out at m*1024+n (final projection)
template <int MODE>
__global__ __launch_bounds__(256, 5) void gemm_bt(const __bf16* __restrict__ A,
                                                  const __bf16* __restrict__ W,
                                                  void* __restrict__ outp) {
    __shared__ alignas(16) __bf16 SM[16384];   // 32 KB: 2 x (A 8KB + B 8KB)
    const int tid = threadIdx.x;
    const int lane = tid & 63, w = tid >> 6;
    const int quad = lane >> 4, l15 = lane & 15;
    const int wy = w >> 1, wx = w & 1;
    const int bm = blockIdx.x * 128, bn = blockIdx.y * 128;

    floatx4 acc[4][4];
    gemm_mainloop(A, W, SM, bm, bn, tid, acc);

    float* of = (float*)outp;
#pragma unroll
    for (int mt = 0; mt < 4; ++mt)
#pragma unroll
        for (int nt = 0; nt < 4; ++nt)
#pragma unroll
            for (int r = 0; r < 4; ++r) {
                int m = bm + wy * 64 + mt * 16 + quad * 4 + r;
                int n = bn + wx * 64 + nt * 16 + l15;
                of[(size_t)m * 1024 + n] = acc[mt][nt][r];
            }
}

// ---------------------------------------------------------------- attention --
// grid (16 q-tiles, 64 bh); block 256; lb(256,4). Wave w owns q rows [w*32, w*32+32).
// 64-key KV tiles, 32 iters. LDS 32KB: Ksm 8KB [8 chunks][64 keys][8], Vsm 8KB
// [8 key-chunks][64 d][8], Psm 16KB (4KB per wave, wave-private -> no fence needed).
// P layout per wave (4KB): [8 chunks][32 rows][8 keys], 16B cells, swizzled:
//   r2 = row ^ (((row>>3)&1)<<1) ^ (c&1)
// Write banks bijective over the 8 written cells -> 32 banks, 2 lanes/bank same-dword
// (free). Read phases (uniform c, 8 consecutive rows) -> conflict-free. [verified R5]

__device__ __forceinline__ int paddr(int c, int row) {
    int r2 = row ^ (((row >> 3) & 1) << 1) ^ (c & 1);
    return (c * 32 + r2) * 16;   // byte offset; 16B per (chunk,row) cell
}

__global__ __launch_bounds__(256, 4) void attn_kernel(const __bf16* __restrict__ Qg,
                                                      const __bf16* __restrict__ Kg,
                                                      const __bf16* __restrict__ Vtg,
                                                      __bf16* __restrict__ ctxg) {
    __shared__ alignas(16) __bf16 Ksm[4096];  // 8KB: K tile (epilogue scratch after loop)
    __shared__ alignas(16) __bf16 Vsm[4096];  // 8KB: V tile
    __shared__ alignas(16) __bf16 Psm[8192];  // 16KB: P, 4KB per wave
    const int tid = threadIdx.x;
    const int w = tid >> 6, lane = tid & 63;
    const int quad = lane >> 4, l15 = lane & 15;
    const int qbase = blockIdx.x * 128;
    const int bh = blockIdx.y;

    char* Pw = (char*)Psm + w * 4096;

    // Q fragments (A-operand): 32 q rows per wave, 2 m-tiles
    bf16x8 qf[2][2];
#pragma unroll
    for (int mt = 0; mt < 2; ++mt) {
        const __bf16* qrow = Qg + ((size_t)bh * 2048 + qbase + w * 32 + mt * 16 + l15) * 64;
        qf[mt][0] = *(const bf16x8*)(qrow + quad * 8);
        qf[mt][1] = *(const bf16x8*)(qrow + 32 + quad * 8);
    }

    float l_p[2][4] = {{0.f, 0.f, 0.f, 0.f}, {0.f, 0.f, 0.f, 0.f}};
    floatx4 o[2][4];
#pragma unroll
    for (int mt = 0; mt < 2; ++mt)
#pragma unroll
        for (int dt = 0; dt < 4; ++dt) o[mt][dt] = (floatx4){0.f, 0.f, 0.f, 0.f};

    for (int kv = 0; kv < 32; ++kv) {
        const int kv0 = kv * 64;
        __syncthreads();  // prev iter's K/V reads done before restaging
#pragma unroll
        for (int j = 0; j < 2; ++j) {
            int base = j * 256 + w * 64;      // wave-uniform cell base
            int flat = base + lane;
            int c = flat >> 6, r = flat & 63;
            GLOAD_LDS16(Kg + ((size_t)bh * 2048 + kv0 + r) * 64 + c * 8, (char*)Ksm + base * 16);
            GLOAD_LDS16(Vtg + ((size_t)bh * 64 + r) * 2048 + kv0 + c * 8, (char*)Vsm + base * 16);
        }
        __syncthreads();  // staging complete

        // scores: 32 q-rows x 64 keys per wave (16 MFMAs)
        floatx4 sa[2][4];
#pragma unroll
        for (int mt = 0; mt < 2; ++mt)
#pragma unroll
            for (int nt = 0; nt < 4; ++nt) sa[mt][nt] = (floatx4){0.f, 0.f, 0.f, 0.f};
#pragma unroll
        for (int nt = 0; nt < 4; ++nt) {
            bf16x8 kb0 = *(const bf16x8*)(Ksm + (quad * 64 + nt * 16 + l15) * 8);
            bf16x8 kb1 = *(const bf16x8*)(Ksm + ((4 + quad) * 64 + nt * 16 + l15) * 8);
#pragma unroll
            for (int mt = 0; mt < 2; ++mt) {
                sa[mt][nt] = __builtin_amdgcn_mfma_f32_16x16x32_bf16(qf[mt][0], kb0,
                                                                    sa[mt][nt], 0, 0, 0);
                sa[mt][nt] = __builtin_amdgcn_mfma_f32_16x16x32_bf16(qf[mt][1], kb1,
                                                                    sa[mt][nt], 0, 0, 0);
            }
        }

        // p = exp2(s) [native]; per-lane l partial; store truncated-bf16 P (swizzled).
        // P is wave-private -> no barrier needed (DS pipe in-order within a wave).
#pragma unroll
        for (int mt = 0; mt < 2; ++mt)
#pragma unroll
            for (int nt = 0; nt < 4; ++nt)
#pragma unroll
                for (int r = 0; r < 4; ++r) {
                    float p = __builtin_amdgcn_exp2f(sa[mt][nt][r]);
                    l_p[mt][r] += p;
                    unsigned u = __builtin_bit_cast(unsigned, p);
                    *(unsigned short*)(Pw + paddr(nt * 2 + (l15 >> 3),
                                                  mt * 16 + quad * 4 + r)
                                       + (l15 & 7) * 2) = (unsigned short)(u >> 16);
                }

        // PV: P (wave-private) @ V  (16 MFMAs)
#pragma unroll
        for (int kk = 0; kk < 2; ++kk) {
            bf16x8 pa0 = *(const bf16x8*)(Pw + paddr(kk * 4 + quad, l15));
            bf16x8 pa1 = *(const bf16x8*)(Pw + paddr(kk * 4 + quad, 16 + l15));
#pragma unroll
            for (int dt = 0; dt < 4; ++dt) {
                bf16x8 vb = *(const bf16x8*)(Vsm + ((kk * 4 + quad) * 64 + dt * 16 + l15) * 8);
                o[0][dt] = __builtin_amdgcn_mfma_f32_16x16x32_bf16(pa0, vb, o[0][dt], 0, 0, 0);
                o[1][dt] = __builtin_amdgcn_mfma_f32_16x16x32_bf16(pa1, vb, o[1][dt], 0, 0, 0);
            }
        }
    }

    __syncthreads();  // all waves done with K/V before epilogue scratch reuse

    // final l reduction across the 16 lanes of each quad-group (cols of each row)
    float inv[2][4];
#pragma unroll
    for (int mt = 0; mt < 2; ++mt)
#pragma unroll
        for (int r = 0; r < 4; ++r) {
            float t = l_p[mt][r];
            t += __shfl_xor(t, 1); t += __shfl_xor(t, 2);
            t += __shfl_xor(t, 4); t += __shfl_xor(t, 8);
            inv[mt][r] = 1.f / t;
        }

    float* tb = (float*)Ksm + w * 272;  // [16][17] per wave (4x272 floats fits 8KB Ksm+Vsm)
    const int bI = bh >> 4, h = bh & 15;
    const int rr = lane >> 2, c0 = (lane & 3) * 4;
#pragma unroll
    for (int mt = 0; mt < 2; ++mt)
#pragma unroll
        for (int dt = 0; dt < 4; ++dt) {
#pragma unroll
            for (int r = 0; r < 4; ++r)
                tb[(quad * 4 + r) * 17 + l15] = o[mt][dt][r] * inv[mt][r];
            // wave-lockstep: DS pipe in-order within a wave
            float f0 = tb[rr * 17 + c0 + 0], f1 = tb[rr * 17 + c0 + 1];
            float f2 = tb[rr * 17 + c0 + 2], f3 = tb[rr * 17 + c0 + 3];
            bf16x4 pk = { (__bf16)f0, (__bf16)f1, (__bf16)f2, (__bf16)f3 };
            *(bf16x4*)(ctxg + ((size_t)(bI * 2048 + qbase + w * 32 + mt * 16 + rr)) * 1024
                       + h * 64 + dt * 16 + c0) = pk;
        }
}

// ---------------------------------------------------------------- launch -----
extern "C" void kernel_launch(void* const* d_in, const int* in_sizes, int n_in,
                              void* d_out, int out_size, void* d_ws, size_t ws_size,
                              hipStream_t stream) {
    const float* x  = (const float*)d_in[0];
    const float* Wq = (const float*)d_in[1];
    const float* Wk = (const float*)d_in[2];
    const float* Wv = (const float*)d_in[3];
    const float* Wo = (const float*)d_in[4];
    float* out = (float*)d_out;
    char* ws = (char*)d_ws;

    // workspace map (72 MB): ctx aliases xb (x dead after QKV GEMMs)
    __bf16* xb  = (__bf16*)(ws);                    // 16 MB
    __bf16* wqb = (__bf16*)(ws + (16u << 20));      // 2 MB each
    __bf16* wkb = (__bf16*)(ws + (18u << 20));
    __bf16* wvb = (__bf16*)(ws + (20u << 20));
    __bf16* wob = (__bf16*)(ws + (22u << 20));
    __bf16* Qg  = (__bf16*)(ws + (24u << 20));      // 16 MB each
    __bf16* Kg  = (__bf16*)(ws + (40u << 20));
    __bf16* Vtg = (__bf16*)(ws + (56u << 20));
    __bf16* ctx = xb;

    // 1/sqrt(64) * log2(e): scores land in exp2 domain
    const float qscale = 0.18033688011112042f;

    cvt_x<<<8192, 256, 0, stream>>>((const float4*)x, (bf16x4*)xb, 2097152);
    cvt_w<<<dim3(1024, 4), 256, 0, stream>>>((const float4*)Wq, (const float4*)Wk,
                                             (const float4*)Wv, (const float4*)Wo,
                                             (bf16x4*)wqb, (bf16x4*)wkb,
                                             (bf16x4*)wvb, (bf16x4*)wob, qscale);

    gemm_qkv<<<dim3(64, 24), 256, 0, stream>>>(xb, wqb, wkb, wvb, Qg, Kg, Vtg);

    attn_kernel<<<dim3(16, 64), 256, 0, stream>>>(Qg, Kg, Vtg, ctx);

    gemm_bt<3><<<dim3(64, 8), 256, 0, stream>>>(ctx, wob, (void*)out);
}

// Round 7
// 336.372 us; speedup vs baseline: 1.0316x; 1.0316x over previous
//
#include <hip/hip_runtime.h>

// MultiHeadAttention: B=4, S=2048, E=1024, H=16, DK=64. fp32 in/out, bf16 MFMA internally.
//
// Pipeline (5 dispatches):
//   cvt_x:    x fp32 -> bf16
//   cvt_w:    Wq,Wk,Wv,Wo fp32 -> bf16 (Wq scaled by 1/sqrt(64)*log2(e) => softmax in exp2 domain)
//   gemm_qkv: Q,K = x@W^T -> (b*H+h, s, d); V = x@Wv^T -> (b*H+h, d, s) transposed  [one dispatch]
//   attn:     flash attention, 128 q-rows/block (32/wave), 64-key KV tiles, NO-MAX softmax
//             (scores bounded ~|9| in exp2 domain), native v_exp_f32, truncated-bf16 P.
//   gemm_bt<3>: out = ctx@Wo^T -> fp32
//
// R7: R6's single-barrier ping-pong reverted (regressed 121->129: vmcnt(0) before s_barrier
// drains the just-issued prefetch anyway; 32KB LDS cut residency). Back to the proven
// two-barrier single-buffer skeleton, but with 128x256 block tiles: 32 MFMAs per wave-iter
// (2x compute per barrier drain), half the total drains. Grid y=bm so the 12 concurrent
// same-A-panel blocks share the L3/L2 fetch of x (A is the L2-cold operand).
//
// MFMA 16x16x32 bf16 layouts (learn_hip verified):
//   A: lane holds A[m=lane&15][k=(lane>>4)*8+j]   B: lane holds B[k=(lane>>4)*8+j][n=lane&15]
//   C/D: col=lane&15, row=(lane>>4)*4+reg
// LDS tiles chunk-major [k-chunk][row][8 elems] -> b128 reads phase-complete (conflict floor).

typedef __bf16 bf16x8 __attribute__((ext_vector_type(8)));
typedef __bf16 bf16x4 __attribute__((ext_vector_type(4)));
typedef float floatx4 __attribute__((ext_vector_type(4)));

#define GLOAD_LDS16(gp, lp) __builtin_amdgcn_global_load_lds( \
    (const __attribute__((address_space(1))) unsigned int*)(gp), \
    (__attribute__((address_space(3))) unsigned int*)(lp), 16, 0, 0)

// ---------------------------------------------------------------- convert ----
__global__ __launch_bounds__(256) void cvt_x(const float4* __restrict__ s,
                                             bf16x4* __restrict__ d, int n4) {
    int i = blockIdx.x * 256 + threadIdx.x;
    if (i < n4) {
        float4 v = s[i];
        bf16x4 o = { (__bf16)v.x, (__bf16)v.y, (__bf16)v.z, (__bf16)v.w };
        d[i] = o;
    }
}

__global__ __launch_bounds__(256) void cvt_w(const float4* __restrict__ Wq,
                                             const float4* __restrict__ Wk,
                                             const float4* __restrict__ Wv,
                                             const float4* __restrict__ Wo,
                                             bf16x4* __restrict__ oq, bf16x4* __restrict__ ok,
                                             bf16x4* __restrict__ ov, bf16x4* __restrict__ oo,
                                             float qscale) {
    int y = blockIdx.y;
    const float4* s = (y == 0) ? Wq : (y == 1) ? Wk : (y == 2) ? Wv : Wo;
    bf16x4* d = (y == 0) ? oq : (y == 1) ? ok : (y == 2) ? ov : oo;
    float scale = (y == 0) ? qscale : 1.0f;
    int i = blockIdx.x * 256 + threadIdx.x;  // 262144 float4 per matrix
    float4 v = s[i];
    bf16x4 o = { (__bf16)(v.x * scale), (__bf16)(v.y * scale),
                 (__bf16)(v.z * scale), (__bf16)(v.w * scale) };
    d[i] = o;
}

// ---------------------------------------------------------------- GEMM core --
// C[m][n] = sum_k A[m][k] * W[n][k], M=8192, N=1024, K=1024. 128x256 block tile, BK=32.
// 4 waves, each computes 64x128 (mt 4 x nt 8). LDS 24KB single-buffered:
//   Asm [4 kchunks][128 rows][8] = 8KB @ SM+0
//   Bsm [4 kchunks][256 rows][8] = 16KB @ SM+4096 (elems)
// Two barriers per K-iter (R5-proven): barrier (prev reads done); stage; barrier; compute.

__device__ __forceinline__ void gemm_mainloop2(const __bf16* __restrict__ A,
                                               const __bf16* __restrict__ W,
                                               __bf16* SM,
                                               int bm, int bn, int tid,
                                               floatx4 acc[4][8]) {
    const int w = tid >> 6, lane = tid & 63;
    const int quad = lane >> 4, l15 = lane & 15;
    const int wy = w >> 1, wx = w & 1;
    __bf16* Asm = SM;
    __bf16* Bsm = SM + 4096;
#pragma unroll
    for (int i = 0; i < 4; ++i)
#pragma unroll
        for (int j = 0; j < 8; ++j) acc[i][j] = (floatx4){0.f, 0.f, 0.f, 0.f};

    for (int k0 = 0; k0 < 1024; k0 += 32) {
        __syncthreads();  // previous iteration's LDS reads complete
        // A: 512 cells (128 rows x 4 kchunks), 2 GLOADs/lane
#pragma unroll
        for (int j = 0; j < 2; ++j) {
            int base = j * 256 + w * 64;      // wave-uniform cell index
            int flat = base + lane;
            int c = flat >> 7, r = flat & 127;
            GLOAD_LDS16(A + (size_t)(bm + r) * 1024 + k0 + c * 8, (char*)Asm + base * 16);
        }
        // B: 1024 cells (256 rows x 4 kchunks), 4 GLOADs/lane
#pragma unroll
        for (int j = 0; j < 4; ++j) {
            int base = j * 256 + w * 64;
            int flat = base + lane;
            int c = flat >> 8, r = flat & 255;
            GLOAD_LDS16(W + (size_t)(bn + r) * 1024 + k0 + c * 8, (char*)Bsm + base * 16);
        }
        __syncthreads();  // staging visible

        bf16x8 af[4], bf[8];
#pragma unroll
        for (int mt = 0; mt < 4; ++mt)
            af[mt] = *(const bf16x8*)(Asm + (quad * 128 + wy * 64 + mt * 16 + l15) * 8);
#pragma unroll
        for (int nt = 0; nt < 8; ++nt)
            bf[nt] = *(const bf16x8*)(Bsm + (quad * 256 + wx * 128 + nt * 16 + l15) * 8);
#pragma unroll
        for (int mt = 0; mt < 4; ++mt)
#pragma unroll
            for (int nt = 0; nt < 8; ++nt)
                acc[mt][nt] = __builtin_amdgcn_mfma_f32_16x16x32_bf16(af[mt], bf[nt],
                                                                      acc[mt][nt], 0, 0, 0);
    }
    __syncthreads();  // all waves done reading LDS before epilogue scratch reuse
}

// Fused QKV: grid (12, 64). blockIdx.x: sel = x>>2 (0:Q 1:K 2:V), bn = (x&3)*256;
// blockIdx.y = bm/128 (x-fastest dispatch -> 12 same-A-panel blocks concurrent).
__global__ __launch_bounds__(256, 2) void gemm_qkv(const __bf16* __restrict__ A,
                                                   const __bf16* __restrict__ Wqb,
                                                   const __bf16* __restrict__ Wkb,
                                                   const __bf16* __restrict__ Wvb,
                                                   __bf16* __restrict__ Qg,
                                                   __bf16* __restrict__ Kg,
                                                   __bf16* __restrict__ Vtg) {
    __shared__ alignas(16) __bf16 SM[12288];   // 24 KB
    const int sel = blockIdx.x >> 2;                      // block-uniform
    const __bf16* W = (sel == 0) ? Wqb : (sel == 1) ? Wkb : Wvb;
    __bf16* ob = (sel == 0) ? Qg : (sel == 1) ? Kg : Vtg;
    const int bm = blockIdx.y * 128, bn = (blockIdx.x & 3) * 256;
    const int tid = threadIdx.x;
    const int w = tid >> 6, lane = tid & 63;
    const int quad = lane >> 4, l15 = lane & 15;
    const int wy = w >> 1, wx = w & 1;

    floatx4 acc[4][8];
    gemm_mainloop2(A, W, SM, bm, bn, tid, acc);

    // bf16 epilogue via per-wave LDS transpose -> 8B stores
    float* tb = (float*)SM + w * 272;  // [16][17] per wave
    const int rr = lane >> 2, c0 = (lane & 3) * 4;
#pragma unroll
    for (int mt = 0; mt < 4; ++mt)
#pragma unroll
        for (int nt = 0; nt < 8; ++nt) {
            if (sel == 2) {
#pragma unroll
                for (int r = 0; r < 4; ++r) tb[l15 * 17 + quad * 4 + r] = acc[mt][nt][r];
            } else {
#pragma unroll
                for (int r = 0; r < 4; ++r) tb[(quad * 4 + r) * 17 + l15] = acc[mt][nt][r];
            }
            // wave-lockstep: DS pipe in-order within a wave
            float f0 = tb[rr * 17 + c0 + 0], f1 = tb[rr * 17 + c0 + 1];
            float f2 = tb[rr * 17 + c0 + 2], f3 = tb[rr * 17 + c0 + 3];
            bf16x4 pk = { (__bf16)f0, (__bf16)f1, (__bf16)f2, (__bf16)f3 };
            if (sel <= 1) {
                int m = bm + wy * 64 + mt * 16 + rr;      // s-row
                int n0 = bn + wx * 128 + nt * 16 + c0;    // 4 consecutive d
                int bI = m >> 11, s = m & 2047, h = n0 >> 6, d0 = n0 & 63;
                *(bf16x4*)(ob + ((size_t)(bI * 16 + h) * 2048 + s) * 64 + d0) = pk;
            } else {
                int m0 = bm + wy * 64 + mt * 16 + c0;     // 4 consecutive s
                int n = bn + wx * 128 + nt * 16 + rr;     // d-row
                int bI = m0 >> 11, s0 = m0 & 2047, h = n >> 6, d = n & 63;
                *(bf16x4*)(ob + ((size_t)(bI * 16 + h) * 64 + d) * 2048 + s0) = pk;
            }
        }
}

// Final projection: fp32 out at m*1024+n. grid (4, 64): bn = x*256, bm = y*128.
__global__ __launch_bounds__(256, 2) void gemm_out(const __bf16* __restrict__ A,
                                                   const __bf16* __restrict__ W,
                                                   float* __restrict__ of) {
    __shared__ alignas(16) __bf16 SM[12288];   // 24 KB
    const int tid = threadIdx.x;
    const int lane = tid & 63, w = tid >> 6;
    const int quad = lane >> 4, l15 = lane & 15;
    const int wy = w >> 1, wx = w & 1;
    const int bm = blockIdx.y * 128, bn = blockIdx.x * 256;

    floatx4 acc[4][8];
    gemm_mainloop2(A, W, SM, bm, bn, tid, acc);

#pragma unroll
    for (int mt = 0; mt < 4; ++mt)
#pragma unroll
        for (int nt = 0; nt < 8; ++nt)
#pragma unroll
            for (int r = 0; r < 4; ++r) {
                int m = bm + wy * 64 + mt * 16 + quad * 4 + r;
                int n = bn + wx * 128 + nt * 16 + l15;
                of[(size_t)m * 1024 + n] = acc[mt][nt][r];
            }
}

// ---------------------------------------------------------------- attention --
// grid (16 q-tiles, 64 bh); block 256; lb(256,4). Wave w owns q rows [w*32, w*32+32).
// 64-key KV tiles, 32 iters. LDS 32KB: Ksm 8KB [8 chunks][64 keys][8], Vsm 8KB
// [8 key-chunks][64 d][8], Psm 16KB (4KB per wave, wave-private -> no fence needed).
// P layout per wave (4KB): [8 chunks][32 rows][8 keys], 16B cells, swizzled:
//   r2 = row ^ (((row>>3)&1)<<1) ^ (c&1)
// Write banks bijective over the 8 written cells -> 32 banks, 2 lanes/bank same-dword
// (free). Read phases (uniform c, 8 consecutive rows) -> conflict-free. [verified R5]

__device__ __forceinline__ int paddr(int c, int row) {
    int r2 = row ^ (((row >> 3) & 1) << 1) ^ (c & 1);
    return (c * 32 + r2) * 16;   // byte offset; 16B per (chunk,row) cell
}

__global__ __launch_bounds__(256, 4) void attn_kernel(const __bf16* __restrict__ Qg,
                                                      const __bf16* __restrict__ Kg,
                                                      const __bf16* __restrict__ Vtg,
                                                      __bf16* __restrict__ ctxg) {
    __shared__ alignas(16) __bf16 Ksm[4096];  // 8KB: K tile (epilogue scratch after loop)
    __shared__ alignas(16) __bf16 Vsm[4096];  // 8KB: V tile
    __shared__ alignas(16) __bf16 Psm[8192];  // 16KB: P, 4KB per wave
    const int tid = threadIdx.x;
    const int w = tid >> 6, lane = tid & 63;
    const int quad = lane >> 4, l15 = lane & 15;
    const int qbase = blockIdx.x * 128;
    const int bh = blockIdx.y;

    char* Pw = (char*)Psm + w * 4096;

    // Q fragments (A-operand): 32 q rows per wave, 2 m-tiles
    bf16x8 qf[2][2];
#pragma unroll
    for (int mt = 0; mt < 2; ++mt) {
        const __bf16* qrow = Qg + ((size_t)bh * 2048 + qbase + w * 32 + mt * 16 + l15) * 64;
        qf[mt][0] = *(const bf16x8*)(qrow + quad * 8);
        qf[mt][1] = *(const bf16x8*)(qrow + 32 + quad * 8);
    }

    float l_p[2][4] = {{0.f, 0.f, 0.f, 0.f}, {0.f, 0.f, 0.f, 0.f}};
    floatx4 o[2][4];
#pragma unroll
    for (int mt = 0; mt < 2; ++mt)
#pragma unroll
        for (int dt = 0; dt < 4; ++dt) o[mt][dt] = (floatx4){0.f, 0.f, 0.f, 0.f};

    for (int kv = 0; kv < 32; ++kv) {
        const int kv0 = kv * 64;
        __syncthreads();  // prev iter's K/V reads done before restaging
#pragma unroll
        for (int j = 0; j < 2; ++j) {
            int base = j * 256 + w * 64;      // wave-uniform cell base
            int flat = base + lane;
            int c = flat >> 6, r = flat & 63;
            GLOAD_LDS16(Kg + ((size_t)bh * 2048 + kv0 + r) * 64 + c * 8, (char*)Ksm + base * 16);
            GLOAD_LDS16(Vtg + ((size_t)bh * 64 + r) * 2048 + kv0 + c * 8, (char*)Vsm + base * 16);
        }
        __syncthreads();  // staging complete

        // scores: 32 q-rows x 64 keys per wave (16 MFMAs)
        floatx4 sa[2][4];
#pragma unroll
        for (int mt = 0; mt < 2; ++mt)
#pragma unroll
            for (int nt = 0; nt < 4; ++nt) sa[mt][nt] = (floatx4){0.f, 0.f, 0.f, 0.f};
#pragma unroll
        for (int nt = 0; nt < 4; ++nt) {
            bf16x8 kb0 = *(const bf16x8*)(Ksm + (quad * 64 + nt * 16 + l15) * 8);
            bf16x8 kb1 = *(const bf16x8*)(Ksm + ((4 + quad) * 64 + nt * 16 + l15) * 8);
#pragma unroll
            for (int mt = 0; mt < 2; ++mt) {
                sa[mt][nt] = __builtin_amdgcn_mfma_f32_16x16x32_bf16(qf[mt][0], kb0,
                                                                    sa[mt][nt], 0, 0, 0);
                sa[mt][nt] = __builtin_amdgcn_mfma_f32_16x16x32_bf16(qf[mt][1], kb1,
                                                                    sa[mt][nt], 0, 0, 0);
            }
        }

        // p = exp2(s) [native]; per-lane l partial; store truncated-bf16 P (swizzled).
        // P is wave-private -> no barrier needed (DS pipe in-order within a wave).
#pragma unroll
        for (int mt = 0; mt < 2; ++mt)
#pragma unroll
            for (int nt = 0; nt < 4; ++nt)
#pragma unroll
                for (int r = 0; r < 4; ++r) {
                    float p = __builtin_amdgcn_exp2f(sa[mt][nt][r]);
                    l_p[mt][r] += p;
                    unsigned u = __builtin_bit_cast(unsigned, p);
                    *(unsigned short*)(Pw + paddr(nt * 2 + (l15 >> 3),
                                                  mt * 16 + quad * 4 + r)
                                       + (l15 & 7) * 2) = (unsigned short)(u >> 16);
                }

        // PV: P (wave-private) @ V  (16 MFMAs)
#pragma unroll
        for (int kk = 0; kk < 2; ++kk) {
            bf16x8 pa0 = *(const bf16x8*)(Pw + paddr(kk * 4 + quad, l15));
            bf16x8 pa1 = *(const bf16x8*)(Pw + paddr(kk * 4 + quad, 16 + l15));
#pragma unroll
            for (int dt = 0; dt < 4; ++dt) {
                bf16x8 vb = *(const bf16x8*)(Vsm + ((kk * 4 + quad) * 64 + dt * 16 + l15) * 8);
                o[0][dt] = __builtin_amdgcn_mfma_f32_16x16x32_bf16(pa0, vb, o[0][dt], 0, 0, 0);
                o[1][dt] = __builtin_amdgcn_mfma_f32_16x16x32_bf16(pa1, vb, o[1][dt], 0, 0, 0);
            }
        }
    }

    __syncthreads();  // all waves done with K/V before epilogue scratch reuse

    // final l reduction across the 16 lanes of each quad-group (cols of each row)
    float inv[2][4];
#pragma unroll
    for (int mt = 0; mt < 2; ++mt)
#pragma unroll
        for (int r = 0; r < 4; ++r) {
            float t = l_p[mt][r];
            t += __shfl_xor(t, 1); t += __shfl_xor(t, 2);
            t += __shfl_xor(t, 4); t += __shfl_xor(t, 8);
            inv[mt][r] = 1.f / t;
        }

    float* tb = (float*)Ksm + w * 272;  // [16][17] per wave (4x272 floats fits Ksm+Vsm)
    const int bI = bh >> 4, h = bh & 15;
    const int rr = lane >> 2, c0 = (lane & 3) * 4;
#pragma unroll
    for (int mt = 0; mt < 2; ++mt)
#pragma unroll
        for (int dt = 0; dt < 4; ++dt) {
#pragma unroll
            for (int r = 0; r < 4; ++r)
                tb[(quad * 4 + r) * 17 + l15] = o[mt][dt][r] * inv[mt][r];
            // wave-lockstep: DS pipe in-order within a wave
            float f0 = tb[rr * 17 + c0 + 0], f1 = tb[rr * 17 + c0 + 1];
            float f2 = tb[rr * 17 + c0 + 2], f3 = tb[rr * 17 + c0 + 3];
            bf16x4 pk = { (__bf16)f0, (__bf16)f1, (__bf16)f2, (__bf16)f3 };
            *(bf16x4*)(ctxg + ((size_t)(bI * 2048 + qbase + w * 32 + mt * 16 + rr)) * 1024
                       + h * 64 + dt * 16 + c0) = pk;
        }
}

// ---------------------------------------------------------------- launch -----
extern "C" void kernel_launch(void* const* d_in, const int* in_sizes, int n_in,
                              void* d_out, int out_size, void* d_ws, size_t ws_size,
                              hipStream_t stream) {
    const float* x  = (const float*)d_in[0];
    const float* Wq = (const float*)d_in[1];
    const float* Wk = (const float*)d_in[2];
    const float* Wv = (const float*)d_in[3];
    const float* Wo = (const float*)d_in[4];
    float* out = (float*)d_out;
    char* ws = (char*)d_ws;

    // workspace map (72 MB): ctx aliases xb (x dead after QKV GEMMs)
    __bf16* xb  = (__bf16*)(ws);                    // 16 MB
    __bf16* wqb = (__bf16*)(ws + (16u << 20));      // 2 MB each
    __bf16* wkb = (__bf16*)(ws + (18u << 20));
    __bf16* wvb = (__bf16*)(ws + (20u << 20));
    __bf16* wob = (__bf16*)(ws + (22u << 20));
    __bf16* Qg  = (__bf16*)(ws + (24u << 20));      // 16 MB each
    __bf16* Kg  = (__bf16*)(ws + (40u << 20));
    __bf16* Vtg = (__bf16*)(ws + (56u << 20));
    __bf16* ctx = xb;

    // 1/sqrt(64) * log2(e): scores land in exp2 domain
    const float qscale = 0.18033688011112042f;

    cvt_x<<<8192, 256, 0, stream>>>((const float4*)x, (bf16x4*)xb, 2097152);
    cvt_w<<<dim3(1024, 4), 256, 0, stream>>>((const float4*)Wq, (const float4*)Wk,
                                             (const float4*)Wv, (const float4*)Wo,
                                             (bf16x4*)wqb, (bf16x4*)wkb,
                                             (bf16x4*)wvb, (bf16x4*)wob, qscale);

    gemm_qkv<<<dim3(12, 64), 256, 0, stream>>>(xb, wqb, wkb, wvb, Qg, Kg, Vtg);

    attn_kernel<<<dim3(16, 64), 256, 0, stream>>>(Qg, Kg, Vtg, ctx);

    gemm_out<<<dim3(4, 64), 256, 0, stream>>>(ctx, wob, out);
}